// Round 14
// baseline (143.212 us; speedup 1.0000x reference)
//
#include <hip/hip_runtime.h>
#include <math.h>

// TopK router via split-bf16 MFMA: logits = x @ W^T, top-2 + softmax.
// x = xh + xl (bf16 RTNE split, per-consumer in-register), W preconverted
// to ws (h/l bf16) by wprep. logits = xh*wh + xh*wl + xl*wh.
//
// Round-14: occupancy + global_load_lds.
// grid 1024 (4 blocks/CU), 512 thr = 8 waves, 16 tok/block, CK=128.
// x staged fp32 HBM->LDS via global_load_lds (1 instr/wave/chunk, zero
// staging VGPRs); swizzle achieved by pre-swizzling the GLOBAL source
// address (LDS dest stays linear). Each wave (kw 0..3, eh 0..1) ds_reads
// its 8 fp32 A values, converts to bf16 h/l in-register, loads B frags
// direct from L2-hot ws, 6 MFMA into acc[1][2] (8 VGPR).
// __launch_bounds__(512,8) forces VGPR<=64 -> 32 waves/CU.
// One {s_waitcnt vmcnt(0); s_barrier} per phase. LDS 16KB/block.

typedef float f32x4 __attribute__((ext_vector_type(4)));
typedef short bf16x8 __attribute__((ext_vector_type(8)));
typedef unsigned int u32;

#define NE 64
#define TOK 16
#define CK 128
#define THREADS 512
#define LDE 68

__device__ __forceinline__ u32 rtne_bf16(float f) {
  u32 u = __builtin_bit_cast(u32, f);
  return (u + 0x7FFFu + ((u >> 16) & 1u)) >> 16;
}
__device__ __forceinline__ float bf16_to_f(u32 h) {
  return __builtin_bit_cast(float, h << 16);
}
// 8 f32 -> packed bf16 high (hp) and low-residual (lp)
__device__ __forceinline__ void cvt8(const f32x4 a, const f32x4 b,
                                     uint4& hp, uint4& lp) {
  const float f[8] = {a.x, a.y, a.z, a.w, b.x, b.y, b.z, b.w};
  u32 h[8], lo[8];
#pragma unroll
  for (int i = 0; i < 8; ++i) {
    h[i]  = rtne_bf16(f[i]);
    lo[i] = rtne_bf16(f[i] - bf16_to_f(h[i]));
  }
  hp = make_uint4(h[0] | (h[1] << 16), h[2] | (h[3] << 16),
                  h[4] | (h[5] << 16), h[6] | (h[7] << 16));
  lp = make_uint4(lo[0] | (lo[1] << 16), lo[2] | (lo[3] << 16),
                  lo[4] | (lo[5] << 16), lo[6] | (lo[7] << 16));
}
// direct HBM->LDS, 16B per lane; LDS dest = wave-uniform base + lane*16
__device__ __forceinline__ void gload16(const void* gsrc, void* ldst) {
  __builtin_amdgcn_global_load_lds(
      (const __attribute__((address_space(1))) void*)gsrc,
      (__attribute__((address_space(3))) void*)ldst, 16, 0, 0);
}

__global__ __launch_bounds__(256)
void wprep(const float* __restrict__ Wg, uint2* __restrict__ Who,
           uint2* __restrict__ Wlo) {
  const int i = blockIdx.x * 256 + threadIdx.x;   // f32x4 index (65536 total)
  const f32x4 v = *((const f32x4*)Wg + i);
  const u32 h0 = rtne_bf16(v.x), h1 = rtne_bf16(v.y);
  const u32 h2 = rtne_bf16(v.z), h3 = rtne_bf16(v.w);
  const u32 l0 = rtne_bf16(v.x - bf16_to_f(h0));
  const u32 l1 = rtne_bf16(v.y - bf16_to_f(h1));
  const u32 l2 = rtne_bf16(v.z - bf16_to_f(h2));
  const u32 l3 = rtne_bf16(v.w - bf16_to_f(h3));
  Who[i] = make_uint2(h0 | (h1 << 16), h2 | (h3 << 16));
  Wlo[i] = make_uint2(l0 | (l1 << 16), l2 | (l3 << 16));
}

__global__ __launch_bounds__(THREADS, 8)
void gemm_topk(const float* __restrict__ x, const u32* __restrict__ Whg,
               const u32* __restrict__ Wlg, float* __restrict__ out_probs,
               float* __restrict__ out_idx, int D) {
  // union: main loop = 2 x 8KB fp32 x-buffers; epilogue = R[4096] floats
  __shared__ __align__(16) char smem[16384];

  const int tid = threadIdx.x;
  const int w   = tid >> 6;        // wave id: kw = w&3, eh = w>>2
  const int l   = tid & 63;
  const int kw  = w & 3;           // K32 window within chunk
  const int eh  = w >> 2;          // expert half (0/1)
  const int m0  = blockIdx.x * TOK;
  const int nCh = D / CK;          // 32 (even)
  const int Du  = D / 2;           // u32 per W row

  const int g   = l >> 4;          // k sub-group (0..3)
  const int r16 = l & 15;

  // ---- stage map: wave w stages rows 2w, 2w+1 (lane l -> row 2w+(l>>5)).
  // LDS dest is linear (base + lane*16); swizzle is applied on the GLOBAL
  // source: LDS[row][blk] holds global[row][blk ^ (row&7)].
  const int rsr = 2 * w + (l >> 5);
  const int bsw = (l & 31) ^ (rsr & 7);
  const float* xstage = x + (size_t)(m0 + rsr) * D + bsw * 4;
  char* dst0 = smem + w * 1024;          // buf0
  char* dst1 = smem + 8192 + w * 1024;   // buf1

  // ---- B fragment bases (u32 units), L2-hot direct-global
  const u32* wh0 = Whg + (size_t)(eh * 32 + 0  + r16) * Du + kw * 16 + g * 4;
  const u32* wh1 = Whg + (size_t)(eh * 32 + 16 + r16) * Du + kw * 16 + g * 4;
  const u32* wl0 = Wlg + (size_t)(eh * 32 + 0  + r16) * Du + kw * 16 + g * 4;
  const u32* wl1 = Wlg + (size_t)(eh * 32 + 16 + r16) * Du + kw * 16 + g * 4;

  // ---- A read address (swizzled): row r16, 16B blks {c0, c0+1} ^ (row&7)
  const int c0   = kw * 8 + g * 2;
  const int aoff0 = r16 * 512 + ((c0       ^ (r16 & 7)) << 4);
  const int aoff1 = r16 * 512 + (((c0 + 1) ^ (r16 & 7)) << 4);

  f32x4 acc[2];
  acc[0] = (f32x4){0.f, 0.f, 0.f, 0.f};
  acc[1] = (f32x4){0.f, 0.f, 0.f, 0.f};

  // prologue: stage chunk 0 into buf0
  gload16(xstage, dst0);
  asm volatile("s_waitcnt vmcnt(0)\n\ts_barrier" ::: "memory");

#define PHASE(cc, RB, WDST)                                                   \
  do {                                                                        \
    if ((cc) + 1 < nCh)                                                       \
      gload16(xstage + (size_t)((cc) + 1) * CK, WDST);                        \
    {                                                                         \
      const f32x4 a0 = *(const f32x4*)(smem + (RB) + aoff0);                  \
      const f32x4 a1 = *(const f32x4*)(smem + (RB) + aoff1);                  \
      uint4 hp, lp;                                                           \
      cvt8(a0, a1, hp, lp);                                                   \
      const bf16x8 ah = __builtin_bit_cast(bf16x8, hp);                       \
      const bf16x8 al = __builtin_bit_cast(bf16x8, lp);                       \
      const size_t ko = (size_t)(cc) * (CK / 2);                              \
      const bf16x8 bh0 = *(const bf16x8*)(wh0 + ko);                          \
      const bf16x8 bh1 = *(const bf16x8*)(wh1 + ko);                          \
      const bf16x8 bl0 = *(const bf16x8*)(wl0 + ko);                          \
      const bf16x8 bl1 = *(const bf16x8*)(wl1 + ko);                          \
      acc[0] = __builtin_amdgcn_mfma_f32_16x16x32_bf16(ah, bh0, acc[0], 0, 0, 0); \
      acc[0] = __builtin_amdgcn_mfma_f32_16x16x32_bf16(ah, bl0, acc[0], 0, 0, 0); \
      acc[0] = __builtin_amdgcn_mfma_f32_16x16x32_bf16(al, bh0, acc[0], 0, 0, 0); \
      acc[1] = __builtin_amdgcn_mfma_f32_16x16x32_bf16(ah, bh1, acc[1], 0, 0, 0); \
      acc[1] = __builtin_amdgcn_mfma_f32_16x16x32_bf16(ah, bl1, acc[1], 0, 0, 0); \
      acc[1] = __builtin_amdgcn_mfma_f32_16x16x32_bf16(al, bh1, acc[1], 0, 0, 0); \
    }                                                                         \
    asm volatile("s_waitcnt vmcnt(0)\n\ts_barrier" ::: "memory");             \
  } while (0)

  for (int c = 0; c < nCh; c += 2) {
    PHASE(c,     0,    dst1);   // read buf0, stage into buf1
    PHASE(c + 1, 8192, dst0);   // read buf1, stage into buf0
  }
#undef PHASE

  __syncthreads();                  // full drain before LDS reuse

  // ---- epilogue: reduce 4 k-windows, decode, top-2 ----
  float* R = (float*)smem;          // [8 waves][2n x 4r][64 lanes] = 16KB
#pragma unroll
  for (int n = 0; n < 2; ++n)
#pragma unroll
    for (int r = 0; r < 4; ++r)
      R[w * 512 + (n * 4 + r) * 64 + l] = acc[n][r];
  __syncthreads();

  // 16 tok x 64 exp = 1024 values; 512 threads x 2
  float vals[2];
  int dsti[2];
#pragma unroll
  for (int i = 0; i < 2; ++i) {
    const int j = tid + i * THREADS;
    const int t = j >> 6, e = j & 63;
    const int ee = e >> 5, nn = (e >> 4) & 1;
    const int rr = t & 3;
    const int ll = (t >> 2) * 16 + (e & 15);
    float v = 0.f;
#pragma unroll
    for (int k = 0; k < 4; ++k)
      v += R[(ee * 4 + k) * 512 + (nn * 4 + rr) * 64 + ll];
    vals[i] = v;
    dsti[i] = t * LDE + e;
  }
  __syncthreads();                  // reads done before aliasing writes
  float* Lf = (float*)smem;         // [16][68]
#pragma unroll
  for (int i = 0; i < 2; ++i) Lf[dsti[i]] = vals[i];
  __syncthreads();

  if (tid < TOK) {
    const float* row = &Lf[tid * LDE];
    float b0 = -INFINITY, b1 = -INFINITY;
    int i0 = 0, i1 = 0;
#pragma unroll
    for (int e = 0; e < NE; ++e) {   // strict '>' = lowest index on ties
      const float val = row[e];
      if (val > b0) { b1 = b0; i1 = i0; b0 = val; i0 = e; }
      else if (val > b1) { b1 = val; i1 = e; }
    }
    const float e1  = expf(b1 - b0);
    const float inv = 1.f / (1.f + e1);
    const int tok = m0 + tid;
    out_probs[tok * 2 + 0] = inv;
    out_probs[tok * 2 + 1] = e1 * inv;
    out_idx[tok * 2 + 0] = (float)i0;
    out_idx[tok * 2 + 1] = (float)i1;
  }
}

// ---- fallback (round-6 fused VALU kernel) if ws is too small ----
typedef float f32x4b __attribute__((ext_vector_type(4)));
#define FEW 8
#define FCK 64
#define FLDT 68
#define FTOK 64
__global__ __launch_bounds__(512, 2)
void router_fused(const float* __restrict__ x, const float* __restrict__ W,
                  float* __restrict__ out_probs, float* __restrict__ out_idx,
                  int D) {
  __shared__ float As[2][FTOK][FLDT];
  const int tid = threadIdx.x;
  const int w = __builtin_amdgcn_readfirstlane(tid >> 6);
  const int lane = tid & 63;
  const int m0 = blockIdx.x * FTOK;
  const int nCh = D / FCK;
  const float* xrow = x + (size_t)(m0 + lane) * D;
  const float* __restrict__ wbase = W + (size_t)(w * FEW) * D;
  float acc[FEW];
#pragma unroll
  for (int e = 0; e < FEW; ++e) acc[e] = 0.f;
  {
    const f32x4b a = *reinterpret_cast<const f32x4b*>(xrow + 4 * w);
    const f32x4b b = *reinterpret_cast<const f32x4b*>(xrow + 4 * (w + 8));
    *reinterpret_cast<f32x4b*>(&As[0][lane][4 * w]) = a;
    *reinterpret_cast<f32x4b*>(&As[0][lane][4 * (w + 8)]) = b;
  }
  __syncthreads();
  for (int c = 0; c < nCh; ++c) {
    const int buf = c & 1;
    f32x4b na, nb;
    const bool more = (c + 1 < nCh);
    if (more) {
      const float* xn = xrow + (size_t)(c + 1) * FCK;
      na = *reinterpret_cast<const f32x4b*>(xn + 4 * w);
      nb = *reinterpret_cast<const f32x4b*>(xn + 4 * (w + 8));
    }
    const float* __restrict__ wp = wbase + (size_t)c * FCK;
#pragma unroll 2
    for (int kk = 0; kk < FCK / 4; ++kk) {
      const f32x4b xvv = *reinterpret_cast<const f32x4b*>(&As[buf][lane][kk * 4]);
#pragma unroll
      for (int e = 0; e < FEW; ++e) {
        const f32x4b wv = *reinterpret_cast<const f32x4b*>(wp + (size_t)e * D + kk * 4);
        acc[e] = fmaf(xvv.x, wv.x, acc[e]);
        acc[e] = fmaf(xvv.y, wv.y, acc[e]);
        acc[e] = fmaf(xvv.z, wv.z, acc[e]);
        acc[e] = fmaf(xvv.w, wv.w, acc[e]);
      }
    }
    __syncthreads();
    if (more) {
      *reinterpret_cast<f32x4b*>(&As[buf ^ 1][lane][4 * w]) = na;
      *reinterpret_cast<f32x4b*>(&As[buf ^ 1][lane][4 * (w + 8)]) = nb;
    }
    __syncthreads();
  }
  float* L = &As[0][0][0];
  *reinterpret_cast<f32x4b*>(&L[lane * FLDT + w * FEW + 0]) =
      (f32x4b){acc[0], acc[1], acc[2], acc[3]};
  *reinterpret_cast<f32x4b*>(&L[lane * FLDT + w * FEW + 4]) =
      (f32x4b){acc[4], acc[5], acc[6], acc[7]};
  __syncthreads();
  if (tid < FTOK) {
    const float* row = &L[tid * FLDT];
    float b0 = -INFINITY, b1 = -INFINITY;
    int i0 = 0, i1 = 0;
#pragma unroll
    for (int e = 0; e < NE; ++e) {
      const float val = row[e];
      if (val > b0) { b1 = b0; i1 = i0; b0 = val; i0 = e; }
      else if (val > b1) { b1 = val; i1 = e; }
    }
    const float e1 = expf(b1 - b0);
    const float inv = 1.f / (1.f + e1);
    const int tok = m0 + tid;
    out_probs[tok * 2 + 0] = inv;
    out_probs[tok * 2 + 1] = e1 * inv;
    out_idx[tok * 2 + 0] = (float)i0;
    out_idx[tok * 2 + 1] = (float)i1;
  }
}

extern "C" void kernel_launch(void* const* d_in, const int* in_sizes, int n_in,
                              void* d_out, int out_size, void* d_ws, size_t ws_size,
                              hipStream_t stream) {
  const float* x = (const float*)d_in[0];
  const float* W = (const float*)d_in[1];

  const int E = 64;
  const int D = in_sizes[1] / E;            // 4096
  const int nTok = in_sizes[0] / D;         // 16384

  float* probs = (float*)d_out;
  float* idxo  = (float*)d_out + (size_t)nTok * 2;

  const size_t wBytes = (size_t)E * D * sizeof(short);   // 512 KB per half
  if (ws_size >= 2 * wBytes) {
    u32* Wh = (u32*)d_ws;
    u32* Wl = (u32*)((char*)d_ws + wBytes);
    hipLaunchKernelGGL(wprep, dim3((E * D / 4) / 256), dim3(256), 0, stream,
                       W, (uint2*)Wh, (uint2*)Wl);
    hipLaunchKernelGGL(gemm_topk, dim3(nTok / TOK), dim3(THREADS), 0, stream,
                       x, Wh, Wl, probs, idxo, D);
  } else {
    hipLaunchKernelGGL(router_fused, dim3(nTok / FTOK), dim3(512), 0, stream,
                       x, W, probs, idxo, D);
  }
}

// Round 15
// 99.552 us; speedup vs baseline: 1.4386x; 1.4386x over previous
//
#include <hip/hip_runtime.h>
#include <math.h>

// TopK router via split-bf16 MFMA: logits = x @ W^T, top-2 + softmax.
// x = xh + xl (bf16 RTNE split), W likewise (preconverted to ws by wprep).
// logits = xh*wh + xh*wl + xl*wh (fp32 MFMA accumulate).
//
// Round-15 = round-12 structure (best: 100us) with ONE change: the h/l
// split uses hardware v_cvt_pk_bf16_f32 (1 instr per 2 elems, RTNE) plus
// exact residual subtraction, instead of ~10 integer VALU ops/elem.
// r14 counters showed the old split cost ~34us of VALU (21% busy) —
// comparable to the 41us HBM floor. Everything else unchanged:
// unroll-4 chunk loop, four named x register sets, nodrain barriers,
// A double-buffered swizzled LDS, B (W h/l) direct global (L2-hot),
// grid 512 (2 blocks/CU), 8 waves, 32 tok/block, VGPR cap 128.

typedef float f32x4 __attribute__((ext_vector_type(4)));
typedef short bf16x8 __attribute__((ext_vector_type(8)));
typedef unsigned int u32;

#define NE 64
#define TOK 32
#define CK 128
#define THREADS 512
#define LDE 68

__device__ __forceinline__ u32 cvtpk(float lo, float hi) {
  u32 r;
  asm("v_cvt_pk_bf16_f32 %0, %1, %2" : "=v"(r) : "v"(lo), "v"(hi));
  return r;
}
__device__ __forceinline__ float asf(u32 u) {
  return __builtin_bit_cast(float, u);
}
// 8 f32 -> packed bf16 high (hp) and low-residual (lp) via v_cvt_pk_bf16_f32.
// Residual x - bf16(x) is exact in fp32 (Sterbenz), then packed RTNE again.
__device__ __forceinline__ void cvt8(const f32x4 a, const f32x4 b,
                                     uint4& hp, uint4& lp) {
  hp.x = cvtpk(a.x, a.y);
  hp.y = cvtpk(a.z, a.w);
  hp.z = cvtpk(b.x, b.y);
  hp.w = cvtpk(b.z, b.w);
  lp.x = cvtpk(a.x - asf(hp.x << 16), a.y - asf(hp.x & 0xFFFF0000u));
  lp.y = cvtpk(a.z - asf(hp.y << 16), a.w - asf(hp.y & 0xFFFF0000u));
  lp.z = cvtpk(b.x - asf(hp.z << 16), b.y - asf(hp.z & 0xFFFF0000u));
  lp.w = cvtpk(b.z - asf(hp.w << 16), b.w - asf(hp.w & 0xFFFF0000u));
}
// LDS byte address: 256B rows (128 bf16), 16B block XOR-swizzled by row
__device__ __forceinline__ int lds_addr(int base, int row, int blk) {
  return base + row * 256 + ((blk ^ (row & 7)) << 4);
}
// barrier that publishes LDS writes but does NOT drain vmem prefetches
__device__ __forceinline__ void barrier_nodrain() {
  asm volatile("s_waitcnt lgkmcnt(0)" ::: "memory");
  __builtin_amdgcn_s_barrier();
}

__global__ __launch_bounds__(256)
void wprep(const float* __restrict__ Wg, uint2* __restrict__ Who,
           uint2* __restrict__ Wlo) {
  const int i = blockIdx.x * 256 + threadIdx.x;   // f32x4 index (65536 total)
  const f32x4 v = *((const f32x4*)Wg + i);
  uint2 hp, lp;
  hp.x = cvtpk(v.x, v.y);
  hp.y = cvtpk(v.z, v.w);
  lp.x = cvtpk(v.x - asf(hp.x << 16), v.y - asf(hp.x & 0xFFFF0000u));
  lp.y = cvtpk(v.z - asf(hp.y << 16), v.w - asf(hp.y & 0xFFFF0000u));
  Who[i] = hp;
  Wlo[i] = lp;
}

__global__ __launch_bounds__(THREADS, 4)
void gemm_topk(const float* __restrict__ x, const u32* __restrict__ Whg,
               const u32* __restrict__ Wlg, float* __restrict__ out_probs,
               float* __restrict__ out_idx, int D) {
  __shared__ __align__(16) char smem[32768];
  // A staging: buf0 h@0 l@8192, buf1 h@16384 l@24576 (32 rows x 256B each)

  const int tid = threadIdx.x;
  const int w   = tid >> 6;
  const int l   = tid & 63;
  const int kw  = w & 3;           // K32 window within chunk
  const int eh  = w >> 2;          // expert half (0/1)
  const int m0  = blockIdx.x * TOK;
  const int nCh = D / CK;          // 32 (assumed >= 8 and divisible by 4)
  const int Du  = D / 2;           // u32 per W row

  const int g   = l >> 4;          // k sub-group
  const int r16 = l & 15;

  // x staging map: thread -> (row=tid>>4, blk=tid&15); 8 f32 = one 16B blk
  const int xr = tid >> 4, xc = tid & 15;
  const float* xg = x + (size_t)(m0 + xr) * D + xc * 8;

  // B fragment bases (u32 units), L2-hot direct-global
  const u32* wh0 = Whg + (size_t)(eh * 32 + 0  + r16) * Du + kw * 16 + g * 4;
  const u32* wh1 = Whg + (size_t)(eh * 32 + 16 + r16) * Du + kw * 16 + g * 4;
  const u32* wl0 = Wlg + (size_t)(eh * 32 + 0  + r16) * Du + kw * 16 + g * 4;
  const u32* wl1 = Wlg + (size_t)(eh * 32 + 16 + r16) * Du + kw * 16 + g * 4;

  f32x4 acc[2][2];
#pragma unroll
  for (int m = 0; m < 2; ++m)
#pragma unroll
    for (int n = 0; n < 2; ++n) acc[m][n] = (f32x4){0.f, 0.f, 0.f, 0.f};

  // four named x register sets (period-4 pipeline, no rotation movs)
  f32x4 xA0, xA1, xB0, xB1, xC0, xC1, xD0, xD1;

  // prologue: load chunks 0..4; convert+publish chunk 0
  {
    f32x4 xT0 = __builtin_nontemporal_load((const f32x4*)xg);
    f32x4 xT1 = __builtin_nontemporal_load((const f32x4*)(xg + 4));
    xA0 = __builtin_nontemporal_load((const f32x4*)(xg + 1 * CK));
    xA1 = __builtin_nontemporal_load((const f32x4*)(xg + 1 * CK + 4));
    xB0 = __builtin_nontemporal_load((const f32x4*)(xg + 2 * CK));
    xB1 = __builtin_nontemporal_load((const f32x4*)(xg + 2 * CK + 4));
    xC0 = __builtin_nontemporal_load((const f32x4*)(xg + 3 * CK));
    xC1 = __builtin_nontemporal_load((const f32x4*)(xg + 3 * CK + 4));
    xD0 = __builtin_nontemporal_load((const f32x4*)(xg + 4 * CK));
    xD1 = __builtin_nontemporal_load((const f32x4*)(xg + 4 * CK + 4));
    uint4 hp, lp;
    cvt8(xT0, xT1, hp, lp);
    *(uint4*)(smem + lds_addr(0,    xr, xc)) = hp;
    *(uint4*)(smem + lds_addr(8192, xr, xc)) = lp;
  }
  __syncthreads();

  // STEP(X, cc): load B(cc); convert X=x(cc+1)->buf; reload X<-x(cc+5);
  //              compute chunk cc; nodrain barrier.
#define STEP(X0, X1, cc)                                                      \
  do {                                                                        \
    const size_t ko = (size_t)(cc) * (CK / 2);                                \
    const bf16x8 bh0 = *(const bf16x8*)(wh0 + ko);                            \
    const bf16x8 bh1 = *(const bf16x8*)(wh1 + ko);                            \
    const bf16x8 bl0 = *(const bf16x8*)(wl0 + ko);                            \
    const bf16x8 bl1 = *(const bf16x8*)(wl1 + ko);                            \
    if ((cc) + 1 < nCh) {                                                     \
      uint4 hp, lp;                                                           \
      cvt8(X0, X1, hp, lp);                                                   \
      const int wb = (((cc) + 1) & 1) * 16384;                                \
      *(uint4*)(smem + lds_addr(wb,        xr, xc)) = hp;                     \
      *(uint4*)(smem + lds_addr(wb + 8192, xr, xc)) = lp;                     \
    }                                                                         \
    if ((cc) + 5 < nCh) {                                                     \
      const float* xn = xg + (size_t)((cc) + 5) * CK;                         \
      X0 = __builtin_nontemporal_load((const f32x4*)xn);                      \
      X1 = __builtin_nontemporal_load((const f32x4*)(xn + 4));                \
    }                                                                         \
    {                                                                         \
      const int rb  = ((cc) & 1) * 16384;                                     \
      const int blk = kw * 4 + g;                                             \
      const bf16x8 ah0 = *(const bf16x8*)(smem + lds_addr(rb,        r16, blk));      \
      const bf16x8 ah1 = *(const bf16x8*)(smem + lds_addr(rb,   16 + r16, blk));      \
      const bf16x8 al0 = *(const bf16x8*)(smem + lds_addr(rb + 8192,      r16, blk)); \
      const bf16x8 al1 = *(const bf16x8*)(smem + lds_addr(rb + 8192, 16 + r16, blk)); \
      acc[0][0] = __builtin_amdgcn_mfma_f32_16x16x32_bf16(ah0, bh0, acc[0][0], 0, 0, 0); \
      acc[0][0] = __builtin_amdgcn_mfma_f32_16x16x32_bf16(ah0, bl0, acc[0][0], 0, 0, 0); \
      acc[0][0] = __builtin_amdgcn_mfma_f32_16x16x32_bf16(al0, bh0, acc[0][0], 0, 0, 0); \
      acc[0][1] = __builtin_amdgcn_mfma_f32_16x16x32_bf16(ah0, bh1, acc[0][1], 0, 0, 0); \
      acc[0][1] = __builtin_amdgcn_mfma_f32_16x16x32_bf16(ah0, bl1, acc[0][1], 0, 0, 0); \
      acc[0][1] = __builtin_amdgcn_mfma_f32_16x16x32_bf16(al0, bh1, acc[0][1], 0, 0, 0); \
      acc[1][0] = __builtin_amdgcn_mfma_f32_16x16x32_bf16(ah1, bh0, acc[1][0], 0, 0, 0); \
      acc[1][0] = __builtin_amdgcn_mfma_f32_16x16x32_bf16(ah1, bl0, acc[1][0], 0, 0, 0); \
      acc[1][0] = __builtin_amdgcn_mfma_f32_16x16x32_bf16(al1, bh0, acc[1][0], 0, 0, 0); \
      acc[1][1] = __builtin_amdgcn_mfma_f32_16x16x32_bf16(ah1, bh1, acc[1][1], 0, 0, 0); \
      acc[1][1] = __builtin_amdgcn_mfma_f32_16x16x32_bf16(ah1, bl1, acc[1][1], 0, 0, 0); \
      acc[1][1] = __builtin_amdgcn_mfma_f32_16x16x32_bf16(al1, bh1, acc[1][1], 0, 0, 0); \
    }                                                                         \
    barrier_nodrain();                                                        \
  } while (0)

  for (int c = 0; c < nCh; c += 4) {
    STEP(xA0, xA1, c);
    STEP(xB0, xB1, c + 1);
    STEP(xC0, xC1, c + 2);
    STEP(xD0, xD1, c + 3);
  }
#undef STEP

  // ---- epilogue: reduce 4 k-windows, decode, top-2 ----
  float* R = (float*)smem;          // [8 waves][16 tr][64 lanes] = 32KB
#pragma unroll
  for (int m = 0; m < 2; ++m)
#pragma unroll
    for (int n = 0; n < 2; ++n)
#pragma unroll
      for (int r = 0; r < 4; ++r)
        R[w * 1024 + ((m * 2 + n) * 4 + r) * 64 + l] = acc[m][n][r];
  __syncthreads();

  // 32 tok x 64 exp = 2048 values; 512 threads x 4
  float vals[4];
  int dsti[4];
#pragma unroll
  for (int i = 0; i < 4; ++i) {
    const int j = tid + i * THREADS;
    const int t = j >> 6, e = j & 63;
    const int mm = t >> 4, nn = (e >> 4) & 1, ee = e >> 5;
    const int rr = t & 3;
    const int ll = ((t & 15) >> 2) * 16 + (e & 15);
    float v = 0.f;
#pragma unroll
    for (int k = 0; k < 4; ++k)
      v += R[(ee * 4 + k) * 1024 + ((mm * 2 + nn) * 4 + rr) * 64 + ll];
    vals[i] = v;
    dsti[i] = t * LDE + e;
  }
  __syncthreads();                  // reads done before aliasing writes
  float* Lf = (float*)smem;         // [32][68]
#pragma unroll
  for (int i = 0; i < 4; ++i) Lf[dsti[i]] = vals[i];
  __syncthreads();

  if (tid < TOK) {
    const float* row = &Lf[tid * LDE];
    float b0 = -INFINITY, b1 = -INFINITY;
    int i0 = 0, i1 = 0;
#pragma unroll
    for (int e = 0; e < NE; ++e) {   // strict '>' = lowest index on ties
      const float val = row[e];
      if (val > b0) { b1 = b0; i1 = i0; b0 = val; i0 = e; }
      else if (val > b1) { b1 = val; i1 = e; }
    }
    const float e1  = expf(b1 - b0);
    const float inv = 1.f / (1.f + e1);
    const int tok = m0 + tid;
    out_probs[tok * 2 + 0] = inv;
    out_probs[tok * 2 + 1] = e1 * inv;
    out_idx[tok * 2 + 0] = (float)i0;
    out_idx[tok * 2 + 1] = (float)i1;
  }
}

// ---- fallback (round-6 fused VALU kernel) if ws is too small ----
#define FEW 8
#define FCK 64
#define FLDT 68
#define FTOK 64
__global__ __launch_bounds__(512, 2)
void router_fused(const float* __restrict__ x, const float* __restrict__ W,
                  float* __restrict__ out_probs, float* __restrict__ out_idx,
                  int D) {
  __shared__ float As[2][FTOK][FLDT];
  const int tid = threadIdx.x;
  const int w = __builtin_amdgcn_readfirstlane(tid >> 6);
  const int lane = tid & 63;
  const int m0 = blockIdx.x * FTOK;
  const int nCh = D / FCK;
  const float* xrow = x + (size_t)(m0 + lane) * D;
  const float* __restrict__ wbase = W + (size_t)(w * FEW) * D;
  float acc[FEW];
#pragma unroll
  for (int e = 0; e < FEW; ++e) acc[e] = 0.f;
  {
    const f32x4 a = *reinterpret_cast<const f32x4*>(xrow + 4 * w);
    const f32x4 b = *reinterpret_cast<const f32x4*>(xrow + 4 * (w + 8));
    *reinterpret_cast<f32x4*>(&As[0][lane][4 * w]) = a;
    *reinterpret_cast<f32x4*>(&As[0][lane][4 * (w + 8)]) = b;
  }
  __syncthreads();
  for (int c = 0; c < nCh; ++c) {
    const int buf = c & 1;
    f32x4 na, nb;
    const bool more = (c + 1 < nCh);
    if (more) {
      const float* xn = xrow + (size_t)(c + 1) * FCK;
      na = *reinterpret_cast<const f32x4*>(xn + 4 * w);
      nb = *reinterpret_cast<const f32x4*>(xn + 4 * (w + 8));
    }
    const float* __restrict__ wp = wbase + (size_t)c * FCK;
#pragma unroll 2
    for (int kk = 0; kk < FCK / 4; ++kk) {
      const f32x4 xvv = *reinterpret_cast<const f32x4*>(&As[buf][lane][kk * 4]);
#pragma unroll
      for (int e = 0; e < FEW; ++e) {
        const f32x4 wv = *reinterpret_cast<const f32x4*>(wp + (size_t)e * D + kk * 4);
        acc[e] = fmaf(xvv.x, wv.x, acc[e]);
        acc[e] = fmaf(xvv.y, wv.y, acc[e]);
        acc[e] = fmaf(xvv.z, wv.z, acc[e]);
        acc[e] = fmaf(xvv.w, wv.w, acc[e]);
      }
    }
    __syncthreads();
    if (more) {
      *reinterpret_cast<f32x4*>(&As[buf ^ 1][lane][4 * w]) = na;
      *reinterpret_cast<f32x4*>(&As[buf ^ 1][lane][4 * (w + 8)]) = nb;
    }
    __syncthreads();
  }
  float* L = &As[0][0][0];
  *reinterpret_cast<f32x4*>(&L[lane * FLDT + w * FEW + 0]) =
      (f32x4){acc[0], acc[1], acc[2], acc[3]};
  *reinterpret_cast<f32x4*>(&L[lane * FLDT + w * FEW + 4]) =
      (f32x4){acc[4], acc[5], acc[6], acc[7]};
  __syncthreads();
  if (tid < FTOK) {
    const float* row = &L[tid * FLDT];
    float b0 = -INFINITY, b1 = -INFINITY;
    int i0 = 0, i1 = 0;
#pragma unroll
    for (int e = 0; e < NE; ++e) {
      const float val = row[e];
      if (val > b0) { b1 = b0; i1 = i0; b0 = val; i0 = e; }
      else if (val > b1) { b1 = val; i1 = e; }
    }
    const float e1 = expf(b1 - b0);
    const float inv = 1.f / (1.f + e1);
    const int tok = m0 + tid;
    out_probs[tok * 2 + 0] = inv;
    out_probs[tok * 2 + 1] = e1 * inv;
    out_idx[tok * 2 + 0] = (float)i0;
    out_idx[tok * 2 + 1] = (float)i1;
  }
}

extern "C" void kernel_launch(void* const* d_in, const int* in_sizes, int n_in,
                              void* d_out, int out_size, void* d_ws, size_t ws_size,
                              hipStream_t stream) {
  const float* x = (const float*)d_in[0];
  const float* W = (const float*)d_in[1];

  const int E = 64;
  const int D = in_sizes[1] / E;            // 4096
  const int nTok = in_sizes[0] / D;         // 16384

  float* probs = (float*)d_out;
  float* idxo  = (float*)d_out + (size_t)nTok * 2;

  const size_t wBytes = (size_t)E * D * sizeof(short);   // 512 KB per half
  if (ws_size >= 2 * wBytes) {
    u32* Wh = (u32*)d_ws;
    u32* Wl = (u32*)((char*)d_ws + wBytes);
    hipLaunchKernelGGL(wprep, dim3((E * D / 4) / 256), dim3(256), 0, stream,
                       W, (uint2*)Wh, (uint2*)Wl);
    hipLaunchKernelGGL(gemm_topk, dim3(nTok / TOK), dim3(THREADS), 0, stream,
                       x, Wh, Wl, probs, idxo, D);
  } else {
    hipLaunchKernelGGL(router_fused, dim3(nTok / FTOK), dim3(512), 0, stream,
                       x, W, probs, idxo, D);
  }
}